// Round 6
// baseline (61.265 us; speedup 1.0000x reference)
//
#include <hip/hip_runtime.h>

#define BB 16384
#define CC 10
#define KK 20
#define DD 128
#define VV 100000
#define NSTREAM 128   // blocks that linearly sweep ctxW to warm L3 (memory-side)

// fast, accurate-enough log sigmoid: logsig(x) = min(x,0) - log(1 + exp(-|x|))
__device__ __forceinline__ float lsg(float x) {
    return fminf(x, 0.0f) - __logf(1.0f + __expf(-fabsf(x)));
}

// butterfly add via ds_swizzle (xor pattern). MASK is ICE.
template <int MASK>
__device__ __forceinline__ float swz_add(float v) {
    int r = __builtin_amdgcn_ds_swizzle(__float_as_int(v), MASK);
    return v + __int_as_float(r);
}

__device__ __forceinline__ float dot4(float4 a, float4 b) {
    return a.x * b.x + a.y * b.y + a.z * b.z + a.w * b.w;
}
__device__ __forceinline__ void add4(float4& a, float4 b) {
    a.x += b.x; a.y += b.y; a.z += b.z; a.w += b.w;
}

// Blocks [0, NSTREAM): stream ctxW linearly (populates L3 at streaming DRAM
// efficiency). Blocks [NSTREAM, NSTREAM + B/16): gather/compute (R4 structure).
__global__ __launch_bounds__(256, 4) void w2v_loss_kernel(
    const int*   __restrict__ context,   // [B, C]
    const int*   __restrict__ target,    // [B]
    const int*   __restrict__ negs,      // [B, K]
    const float* __restrict__ embW,      // [V, D]
    const float* __restrict__ ctxW,      // [V, D]
    float*       __restrict__ block_part // [B/16]
) {
    const int tid = threadIdx.x;
    const float4* ctxW4 = reinterpret_cast<const float4*>(ctxW);

    if (blockIdx.x < NSTREAM) {
        // ---- streamer: linear sweep of ctxW, result kept alive via asm ----
        const int total = VV * (DD / 4);                    // 3.2e6 float4
        const int chunk = (total + NSTREAM - 1) / NSTREAM;  // 25000 float4
        const int lo = blockIdx.x * chunk;
        const int hi = (lo + chunk < total) ? lo + chunk : total;
        float4 acc = make_float4(0.f, 0.f, 0.f, 0.f);
        for (int i = lo + tid; i < hi; i += 256) {
            const float4 v = ctxW4[i];
            acc.x += v.x; acc.y += v.y; acc.z += v.z; acc.w += v.w;
        }
        asm volatile("" :: "v"(acc.x), "v"(acc.y), "v"(acc.z), "v"(acc.w));
        return;
    }

    const int bid   = blockIdx.x - NSTREAM;
    const int wave  = tid >> 6;
    const int lane  = tid & 63;
    const int group = lane >> 4;
    const int gl    = lane & 15;
    const int bl    = wave * 4 + group;
    const int b0    = bid * 16;

    __shared__ int s_ctx[16 * CC];
    __shared__ int s_tgt[16];
    __shared__ int s_neg[16 * KK];
    __shared__ float sp[4];

    if (tid < 16 * CC) s_ctx[tid] = context[b0 * CC + tid];
    if (tid < 16)      s_tgt[tid] = target[b0 + tid];
    s_neg[tid] = negs[b0 * KK + tid];
    if (tid < 16 * KK - 256) s_neg[256 + tid] = negs[b0 * KK + 256 + tid];
    __syncthreads();

    const float4* embW4 = reinterpret_cast<const float4*>(embW);

    // ---- context mean ----
    float4 accA = make_float4(0.f, 0.f, 0.f, 0.f);
    float4 accB = make_float4(0.f, 0.f, 0.f, 0.f);
    #pragma unroll
    for (int c = 0; c < CC; ++c) {
        const int row = s_ctx[bl * CC + c] * (DD / 4);
        const float4 vA = ctxW4[row + gl];
        const float4 vB = ctxW4[row + 16 + gl];
        add4(accA, vA); add4(accB, vB);
    }
    const float inv = 1.0f / CC;
    accA.x *= inv; accA.y *= inv; accA.z *= inv; accA.w *= inv;
    accB.x *= inv; accB.y *= inv; accB.z *= inv; accB.w *= inv;

    // ---- target dot partial ----
    const int trow = s_tgt[bl] * (DD / 4);
    float pd = dot4(accA, embW4[trow + gl]) + dot4(accB, embW4[trow + 16 + gl]);

    // ---- negative dot partials ----
    float nd[KK];
    #pragma unroll
    for (int k = 0; k < KK; ++k) {
        const int row = s_neg[bl * KK + k] * (DD / 4);
        const float4 vA = ctxW4[row + gl];
        const float4 vB = ctxW4[row + 16 + gl];
        nd[k] = dot4(accA, vA) + dot4(accB, vB);
    }

    // ---- reduce over the 16 lanes of the group: xor 1,2,4,8 via ds_swizzle ----
    pd = swz_add<0x041F>(pd);
    #pragma unroll
    for (int k = 0; k < KK; ++k) nd[k] = swz_add<0x041F>(nd[k]);
    pd = swz_add<0x081F>(pd);
    #pragma unroll
    for (int k = 0; k < KK; ++k) nd[k] = swz_add<0x081F>(nd[k]);
    pd = swz_add<0x101F>(pd);
    #pragma unroll
    for (int k = 0; k < KK; ++k) nd[k] = swz_add<0x101F>(nd[k]);
    pd = swz_add<0x201F>(pd);
    #pragma unroll
    for (int k = 0; k < KK; ++k) nd[k] = swz_add<0x201F>(nd[k]);

    // ---- per-b score ----
    float score = lsg(pd);
    #pragma unroll
    for (int k = 0; k < KK; ++k) score += lsg(-nd[k]);

    // ---- combine 4 groups: xor16 (swizzle) + xor32 (shfl) ----
    float s = swz_add<0x401F>(score);
    s += __shfl_xor(s, 32, 64);

    if (lane == 0) sp[wave] = s;
    __syncthreads();
    if (tid == 0)
        block_part[bid] = sp[0] + sp[1] + sp[2] + sp[3];
}

__global__ __launch_bounds__(256) void w2v_finish_kernel(
    const float* __restrict__ part, float* __restrict__ out, int n, float scale)
{
    __shared__ float sm[4];
    float s = 0.f;
    for (int i = threadIdx.x; i < n; i += 256) s += part[i];
    #pragma unroll
    for (int off = 32; off; off >>= 1) s += __shfl_xor(s, off, 64);
    const int wave = threadIdx.x >> 6;
    const int lane = threadIdx.x & 63;
    if (lane == 0) sm[wave] = s;
    __syncthreads();
    if (threadIdx.x == 0) out[0] = (sm[0] + sm[1] + sm[2] + sm[3]) * scale;
}

extern "C" void kernel_launch(void* const* d_in, const int* in_sizes, int n_in,
                              void* d_out, int out_size, void* d_ws, size_t ws_size,
                              hipStream_t stream) {
    const int*   context = (const int*)d_in[0];
    const int*   target  = (const int*)d_in[1];
    const int*   negs    = (const int*)d_in[2];
    const float* embW    = (const float*)d_in[3];
    const float* ctxW    = (const float*)d_in[4];
    float* out = (float*)d_out;

    float* block_part = (float*)d_ws;              // 1024 floats = 4 KB scratch
    const int nblocks = NSTREAM + BB / 16;         // 128 streamers + 1024 gatherers

    w2v_loss_kernel<<<nblocks, 256, 0, stream>>>(context, target, negs, embW, ctxW, block_part);
    w2v_finish_kernel<<<1, 256, 0, stream>>>(block_part, out, BB / 16, -1.0f / (float)BB);
}

// Round 7
// 52.887 us; speedup vs baseline: 1.1584x; 1.1584x over previous
//
#include <hip/hip_runtime.h>

#define BB 16384
#define CC 10
#define KK 20
#define DD 128
#define VV 100000

// fast, accurate-enough log sigmoid: logsig(x) = min(x,0) - log(1 + exp(-|x|))
__device__ __forceinline__ float lsg(float x) {
    return fminf(x, 0.0f) - __logf(1.0f + __expf(-fabsf(x)));
}

// butterfly add via ds_swizzle (xor pattern). MASK is ICE.
template <int MASK>
__device__ __forceinline__ float swz_add(float v) {
    int r = __builtin_amdgcn_ds_swizzle(__float_as_int(v), MASK);
    return v + __int_as_float(r);
}

__device__ __forceinline__ float dot4(float4 a, float4 b) {
    return a.x * b.x + a.y * b.y + a.z * b.z + a.w * b.w;
}
__device__ __forceinline__ void add4(float4& a, float4 b) {
    a.x += b.x; a.y += b.y; a.z += b.z; a.w += b.w;
}

// ---- serial L3 warm: whole device streams ctxW sequentially ----
__global__ __launch_bounds__(256) void w2v_sweep_kernel(
    const float4* __restrict__ p, int n4)
{
    float4 acc = make_float4(0.f, 0.f, 0.f, 0.f);
    for (int i = blockIdx.x * 256 + threadIdx.x; i < n4; i += 2048 * 256) {
        const float4 v = p[i];
        acc.x += v.x; acc.y += v.y; acc.z += v.z; acc.w += v.w;
    }
    asm volatile("" :: "v"(acc.x), "v"(acc.y), "v"(acc.z), "v"(acc.w));
}

// 16 lanes per b, 4 b per wave, 16 b per block (R4 structure, 41.0 us known).
__global__ __launch_bounds__(256, 4) void w2v_loss_kernel(
    const int*   __restrict__ context,   // [B, C]
    const int*   __restrict__ target,    // [B]
    const int*   __restrict__ negs,      // [B, K]
    const float* __restrict__ embW,      // [V, D]
    const float* __restrict__ ctxW,      // [V, D]
    float*       __restrict__ block_part // [B/16]
) {
    const int tid   = threadIdx.x;
    const int wave  = tid >> 6;
    const int lane  = tid & 63;
    const int group = lane >> 4;
    const int gl    = lane & 15;
    const int bl    = wave * 4 + group;
    const int b0    = blockIdx.x * 16;

    __shared__ int s_ctx[16 * CC];
    __shared__ int s_tgt[16];
    __shared__ int s_neg[16 * KK];
    __shared__ float sp[4];

    if (tid < 16 * CC) s_ctx[tid] = context[b0 * CC + tid];
    if (tid < 16)      s_tgt[tid] = target[b0 + tid];
    s_neg[tid] = negs[b0 * KK + tid];
    if (tid < 16 * KK - 256) s_neg[256 + tid] = negs[b0 * KK + 256 + tid];
    __syncthreads();

    const float4* ctxW4 = reinterpret_cast<const float4*>(ctxW);
    const float4* embW4 = reinterpret_cast<const float4*>(embW);

    // ---- context mean ----
    float4 accA = make_float4(0.f, 0.f, 0.f, 0.f);
    float4 accB = make_float4(0.f, 0.f, 0.f, 0.f);
    #pragma unroll
    for (int c = 0; c < CC; ++c) {
        const int row = s_ctx[bl * CC + c] * (DD / 4);
        const float4 vA = ctxW4[row + gl];
        const float4 vB = ctxW4[row + 16 + gl];
        add4(accA, vA); add4(accB, vB);
    }
    const float inv = 1.0f / CC;
    accA.x *= inv; accA.y *= inv; accA.z *= inv; accA.w *= inv;
    accB.x *= inv; accB.y *= inv; accB.z *= inv; accB.w *= inv;

    // ---- target dot partial ----
    const int trow = s_tgt[bl] * (DD / 4);
    float pd = dot4(accA, embW4[trow + gl]) + dot4(accB, embW4[trow + 16 + gl]);

    // ---- negative dot partials ----
    float nd[KK];
    #pragma unroll
    for (int k = 0; k < KK; ++k) {
        const int row = s_neg[bl * KK + k] * (DD / 4);
        const float4 vA = ctxW4[row + gl];
        const float4 vB = ctxW4[row + 16 + gl];
        nd[k] = dot4(accA, vA) + dot4(accB, vB);
    }

    // ---- reduce over the 16 lanes of the group: xor 1,2,4,8 via ds_swizzle ----
    pd = swz_add<0x041F>(pd);
    #pragma unroll
    for (int k = 0; k < KK; ++k) nd[k] = swz_add<0x041F>(nd[k]);
    pd = swz_add<0x081F>(pd);
    #pragma unroll
    for (int k = 0; k < KK; ++k) nd[k] = swz_add<0x081F>(nd[k]);
    pd = swz_add<0x101F>(pd);
    #pragma unroll
    for (int k = 0; k < KK; ++k) nd[k] = swz_add<0x101F>(nd[k]);
    pd = swz_add<0x201F>(pd);
    #pragma unroll
    for (int k = 0; k < KK; ++k) nd[k] = swz_add<0x201F>(nd[k]);

    // ---- per-b score ----
    float score = lsg(pd);
    #pragma unroll
    for (int k = 0; k < KK; ++k) score += lsg(-nd[k]);

    // ---- combine 4 groups: xor16 (swizzle) + xor32 (shfl) ----
    float s = swz_add<0x401F>(score);
    s += __shfl_xor(s, 32, 64);

    if (lane == 0) sp[wave] = s;
    __syncthreads();
    if (tid == 0)
        block_part[blockIdx.x] = sp[0] + sp[1] + sp[2] + sp[3];
}

__global__ __launch_bounds__(256) void w2v_finish_kernel(
    const float* __restrict__ part, float* __restrict__ out, int n, float scale)
{
    __shared__ float sm[4];
    float s = 0.f;
    for (int i = threadIdx.x; i < n; i += 256) s += part[i];
    #pragma unroll
    for (int off = 32; off; off >>= 1) s += __shfl_xor(s, off, 64);
    const int wave = threadIdx.x >> 6;
    const int lane = threadIdx.x & 63;
    if (lane == 0) sm[wave] = s;
    __syncthreads();
    if (threadIdx.x == 0) out[0] = (sm[0] + sm[1] + sm[2] + sm[3]) * scale;
}

extern "C" void kernel_launch(void* const* d_in, const int* in_sizes, int n_in,
                              void* d_out, int out_size, void* d_ws, size_t ws_size,
                              hipStream_t stream) {
    const int*   context = (const int*)d_in[0];
    const int*   target  = (const int*)d_in[1];
    const int*   negs    = (const int*)d_in[2];
    const float* embW    = (const float*)d_in[3];
    const float* ctxW    = (const float*)d_in[4];
    float* out = (float*)d_out;

    float* block_part = (float*)d_ws;          // 1024 floats = 4 KB scratch
    const int nblocks = BB / 16;               // 1024 blocks x 16 b's

    // serial warm: bring ctxW into L3 at streaming DRAM efficiency, THEN gather
    w2v_sweep_kernel<<<2048, 256, 0, stream>>>(
        reinterpret_cast<const float4*>(ctxW), VV * (DD / 4));
    w2v_loss_kernel<<<nblocks, 256, 0, stream>>>(context, target, negs, embW, ctxW, block_part);
    w2v_finish_kernel<<<1, 256, 0, stream>>>(block_part, out, nblocks, -1.0f / (float)BB);
}

// Round 8
// 44.699 us; speedup vs baseline: 1.3706x; 1.1832x over previous
//
#include <hip/hip_runtime.h>

#define BB 16384
#define CC 10
#define KK 20
#define DD 128

// fast, accurate-enough log sigmoid: logsig(x) = min(x,0) - log(1 + exp(-|x|))
__device__ __forceinline__ float lsg(float x) {
    return fminf(x, 0.0f) - __logf(1.0f + __expf(-fabsf(x)));
}

// butterfly add via ds_swizzle (xor pattern). MASK is ICE.
template <int MASK>
__device__ __forceinline__ float swz_add(float v) {
    int r = __builtin_amdgcn_ds_swizzle(__float_as_int(v), MASK);
    return v + __int_as_float(r);
}

__device__ __forceinline__ float dot4(float4 a, float4 b) {
    return a.x * b.x + a.y * b.y + a.z * b.z + a.w * b.w;
}
__device__ __forceinline__ void add4(float4& a, float4 b) {
    a.x += b.x; a.y += b.y; a.z += b.z; a.w += b.w;
}

// 32 lanes per b, 2 b per wave, 8 b per block -> 2048 blocks = 8 blocks/CU
// = 32 waves/CU grid residency. NO min-waves clamp: compiler picks ~40-50
// VGPR (<=64 keeps 8 waves/SIMD eligible), no spills (R3's confound).
__global__ __launch_bounds__(256) void w2v_loss_kernel(
    const int*   __restrict__ context,   // [B, C]
    const int*   __restrict__ target,    // [B]
    const int*   __restrict__ negs,      // [B, K]
    const float* __restrict__ embW,      // [V, D]
    const float* __restrict__ ctxW,      // [V, D]
    float*       __restrict__ block_part // [B/8]
) {
    const int tid   = threadIdx.x;
    const int wave  = tid >> 6;
    const int lane  = tid & 63;
    const int group = lane >> 5;          // 2 groups of 32 lanes per wave
    const int gl    = lane & 31;          // lane owns one float4 of the 512 B row
    const int bl    = wave * 2 + group;   // 0..7 local batch element
    const int b0    = blockIdx.x * 8;

    __shared__ int s_ctx[8 * CC];    // 80
    __shared__ int s_tgt[8];
    __shared__ int s_neg[8 * KK];    // 160
    __shared__ float sp[4];

    if (tid < 8 * CC) s_ctx[tid] = context[b0 * CC + tid];
    if (tid < 8)      s_tgt[tid] = target[b0 + tid];
    if (tid < 8 * KK) s_neg[tid] = negs[b0 * KK + tid];
    __syncthreads();

    const float4* ctxW4 = reinterpret_cast<const float4*>(ctxW);
    const float4* embW4 = reinterpret_cast<const float4*>(embW);

    // ---- context mean ----
    float4 acc = make_float4(0.f, 0.f, 0.f, 0.f);
    #pragma unroll
    for (int c = 0; c < CC; ++c) {
        const int row = s_ctx[bl * CC + c] * (DD / 4);
        add4(acc, ctxW4[row + gl]);
    }
    const float inv = 1.0f / CC;
    acc.x *= inv; acc.y *= inv; acc.z *= inv; acc.w *= inv;

    // ---- target dot partial ----
    const int trow = s_tgt[bl] * (DD / 4);
    float pd = dot4(acc, embW4[trow + gl]);

    // ---- negative dot partials (simple loop: compiler schedules MLP) ----
    float nd[KK];
    #pragma unroll
    for (int k = 0; k < KK; ++k) {
        const int row = s_neg[bl * KK + k] * (DD / 4);
        nd[k] = dot4(acc, ctxW4[row + gl]);
    }

    // ---- reduce over the 32 lanes: xor 1,2,4,8,16 via ds_swizzle ----
    pd = swz_add<0x041F>(pd);
    #pragma unroll
    for (int k = 0; k < KK; ++k) nd[k] = swz_add<0x041F>(nd[k]);
    pd = swz_add<0x081F>(pd);
    #pragma unroll
    for (int k = 0; k < KK; ++k) nd[k] = swz_add<0x081F>(nd[k]);
    pd = swz_add<0x101F>(pd);
    #pragma unroll
    for (int k = 0; k < KK; ++k) nd[k] = swz_add<0x101F>(nd[k]);
    pd = swz_add<0x201F>(pd);
    #pragma unroll
    for (int k = 0; k < KK; ++k) nd[k] = swz_add<0x201F>(nd[k]);
    pd = swz_add<0x401F>(pd);
    #pragma unroll
    for (int k = 0; k < KK; ++k) nd[k] = swz_add<0x401F>(nd[k]);

    // ---- per-b score (2 b's of this wave in parallel) ----
    float score = lsg(pd);
    #pragma unroll
    for (int k = 0; k < KK; ++k) score += lsg(-nd[k]);

    // ---- combine the 2 groups of this wave ----
    float s = score + __shfl_xor(score, 32, 64);

    if (lane == 0) sp[wave] = s;
    __syncthreads();
    if (tid == 0)
        block_part[blockIdx.x] = sp[0] + sp[1] + sp[2] + sp[3];
}

__global__ __launch_bounds__(256) void w2v_finish_kernel(
    const float* __restrict__ part, float* __restrict__ out, int n, float scale)
{
    __shared__ float sm[4];
    float s = 0.f;
    for (int i = threadIdx.x; i < n; i += 256) s += part[i];
    #pragma unroll
    for (int off = 32; off; off >>= 1) s += __shfl_xor(s, off, 64);
    const int wave = threadIdx.x >> 6;
    const int lane = threadIdx.x & 63;
    if (lane == 0) sm[wave] = s;
    __syncthreads();
    if (threadIdx.x == 0) out[0] = (sm[0] + sm[1] + sm[2] + sm[3]) * scale;
}

extern "C" void kernel_launch(void* const* d_in, const int* in_sizes, int n_in,
                              void* d_out, int out_size, void* d_ws, size_t ws_size,
                              hipStream_t stream) {
    const int*   context = (const int*)d_in[0];
    const int*   target  = (const int*)d_in[1];
    const int*   negs    = (const int*)d_in[2];
    const float* embW    = (const float*)d_in[3];
    const float* ctxW    = (const float*)d_in[4];
    float* out = (float*)d_out;

    float* block_part = (float*)d_ws;          // 2048 floats = 8 KB scratch
    const int nblocks = BB / 8;                // 2048 blocks x 8 b's

    w2v_loss_kernel<<<nblocks, 256, 0, stream>>>(context, target, negs, embW, ctxW, block_part);
    w2v_finish_kernel<<<1, 256, 0, stream>>>(block_part, out, nblocks, -1.0f / (float)BB);
}